// Round 5
// baseline (376.278 us; speedup 1.0000x reference)
//
#include <hip/hip_runtime.h>
#include <hip/hip_bf16.h>

using bf16 = __bf16;
typedef __bf16 bf16x4 __attribute__((ext_vector_type(4)));
typedef __bf16 bf16x8 __attribute__((ext_vector_type(8)));
typedef float f32x4 __attribute__((ext_vector_type(4)));

static constexpr int BATCH = 4;
static constexpr int SEQ   = 2048;
static constexpr int DIN   = 512;
static constexpr int NHEAD = 8;
static constexpr int DMID  = 2048;
static constexpr int MROWS = BATCH * SEQ;   // 8192

// ---------------------------------------------------------------------------
// global -> LDS direct DMA, 16 B per lane (global_load_lds_dwordx4).
// ---------------------------------------------------------------------------
__device__ __forceinline__ void gload16(const void* g, void* l)
{
    __builtin_amdgcn_global_load_lds(
        (const __attribute__((address_space(1))) unsigned int*)g,
        (__attribute__((address_space(3))) unsigned int*)l, 16, 0, 0);
}

// ---------------------------------------------------------------------------
// LDS hardware transpose read: 4 bf16, element j = lds[addr + j*16 elems].
// Per-lane addr supplies the (l&15) + (l>>4)*row_window pattern (m156).
// ---------------------------------------------------------------------------
__device__ __forceinline__ bf16x4 ds_tr16(const bf16* p)
{
    bf16x4 r;
    auto lp = (const __attribute__((address_space(3))) bf16*)p;
    asm volatile("ds_read_b64_tr_b16 %0, %1" : "=&v"(r) : "v"(lp) : "memory");
    return r;
}

// ---------------------------------------------------------------------------
// FUSED: six weight transposes (blocks 0..3071) + mask nonzero check
// (3072..4095) + q/k/v fp32->bf16 cast (4096..7167, into Mid alias).
// ---------------------------------------------------------------------------
__global__ __launch_bounds__(256) void tw_mask(
    const float* __restrict__ WQ, const float* __restrict__ WK,
    const float* __restrict__ WV, const float* __restrict__ WO,
    const float* __restrict__ W1, const float* __restrict__ W2,
    bf16* __restrict__ WQt, bf16* __restrict__ WKt, bf16* __restrict__ WVt,
    bf16* __restrict__ WOt, bf16* __restrict__ W1t, bf16* __restrict__ W2t,
    const float* __restrict__ q, const float* __restrict__ k,
    const float* __restrict__ v,
    bf16* __restrict__ qb, bf16* __restrict__ kb, bf16* __restrict__ vb,
    const uint4* __restrict__ mask, int* __restrict__ flag)
{
    const int bid = blockIdx.x;
    if (bid >= 4096) {
        // cast: 1024 blocks per tensor, 4096 floats per block, coalesced
        const int idx = bid - 4096;
        const float* src = idx < 1024 ? q : idx < 2048 ? k : v;
        bf16*       dst = idx < 1024 ? qb : idx < 2048 ? kb : vb;
        const size_t b4 = (size_t)(idx & 1023) * 1024;   // float4 units
#pragma unroll
        for (int i = 0; i < 4; ++i) {
            const float4 f = reinterpret_cast<const float4*>(src)[b4 + i * 256 + threadIdx.x];
            bf16x4 h;
            h[0] = (bf16)f.x; h[1] = (bf16)f.y; h[2] = (bf16)f.z; h[3] = (bf16)f.w;
            reinterpret_cast<bf16x4*>(dst)[b4 + i * 256 + threadIdx.x] = h;
        }
        return;
    }
    if (bid >= 3072) {
        const uint4* p = mask + (size_t)(bid - 3072) * 4096;
        unsigned nz = 0;
#pragma unroll
        for (int i = 0; i < 16; ++i) {
            const uint4 u = p[i * 256 + threadIdx.x];
            nz |= u.x | u.y | u.z | u.w;
        }
        if (nz) atomicOr(flag, 1);
        return;
    }
    __shared__ float tile[32][33];
    const float* in; bf16* out; int ip, op, cx, ry;
    if (bid < 1024) {
        const int w = bid >> 8, idx = bid & 255;
        in  = w == 0 ? WQ  : w == 1 ? WK  : w == 2 ? WV  : WO;
        out = w == 0 ? WQt : w == 1 ? WKt : w == 2 ? WVt : WOt;
        ip = 512; op = 512; cx = idx & 15; ry = idx >> 4;
    } else if (bid < 2048) {
        const int idx = bid - 1024;
        in = W1; out = W1t; ip = 2048; op = 512; cx = idx & 63; ry = idx >> 6;
    } else {
        const int idx = bid - 2048;
        in = W2; out = W2t; ip = 512; op = 2048; cx = idx & 15; ry = idx >> 4;
    }
    const int c0 = cx * 32, r0 = ry * 32;
    const int tx = threadIdx.x & 31, ty = threadIdx.x >> 5;
    for (int i = 0; i < 32; i += 8)
        tile[ty + i][tx] = in[(size_t)(r0 + ty + i) * ip + c0 + tx];
    __syncthreads();
    for (int i = 0; i < 32; i += 8)
        out[(size_t)(c0 + ty + i) * op + r0 + tx] = (bf16)tile[tx][ty + i];
}

// ---------------------------------------------------------------------------
// 128x128-tile GEMM (m97 structure) for W1 (N=2048). BK=64, 4 waves.
// ---------------------------------------------------------------------------
template <int ACT>
__global__ __launch_bounds__(256) void gemm128(const bf16* __restrict__ A,
                                               const bf16* __restrict__ Bt,
                                               bf16* __restrict__ C,
                                               int N, int K)
{
    __shared__ bf16 sA[128 * 64];
    __shared__ bf16 sB[128 * 64];

    const int t    = threadIdx.x;
    const int lane = t & 63;
    const int wave = t >> 6;
    const int wm   = wave >> 1;
    const int wn   = wave & 1;
    const int lr   = lane & 15;
    const int lq   = lane >> 4;

    const int m0 = blockIdx.y * 128;
    const int n0 = blockIdx.x * 128;

    const int srow = lane >> 3;
    const int scol = (lane & 7) * 8;

    f32x4 acc[4][4] = {};

    for (int k0 = 0; k0 < K; k0 += 64) {
        if (k0) __syncthreads();
#pragma unroll
        for (int i = 0; i < 4; ++i) {
            const int ch = wave * 4 + i;
            const int r  = ch * 8 + srow;
            gload16(A  + (size_t)(m0 + r) * K + k0 + scol, sA + ch * 512);
            gload16(Bt + (size_t)(n0 + r) * K + k0 + scol, sB + ch * 512);
        }
        __syncthreads();

#pragma unroll
        for (int kk = 0; kk < 2; ++kk) {
            bf16x8 af[4], bfr[4];
#pragma unroll
            for (int x = 0; x < 4; ++x) {
                af[x]  = *reinterpret_cast<const bf16x8*>(&sA[(wm * 64 + x * 16 + lr) * 64 + kk * 32 + lq * 8]);
                bfr[x] = *reinterpret_cast<const bf16x8*>(&sB[(wn * 64 + x * 16 + lr) * 64 + kk * 32 + lq * 8]);
            }
#pragma unroll
            for (int m = 0; m < 4; ++m)
#pragma unroll
                for (int n = 0; n < 4; ++n)
                    acc[m][n] = __builtin_amdgcn_mfma_f32_16x16x32_bf16(af[m], bfr[n], acc[m][n], 0, 0, 0);
        }
    }

#pragma unroll
    for (int n = 0; n < 4; ++n) {
        const int col = n0 + wn * 64 + n * 16 + lr;
#pragma unroll
        for (int m = 0; m < 4; ++m) {
            const int rowb = m0 + wm * 64 + m * 16 + lq * 4;
#pragma unroll
            for (int j = 0; j < 4; ++j) {
                float v = acc[m][n][j];
                if (ACT == 1) v = v > 0.f ? v : 0.f;
                C[(size_t)(rowb + j) * N + col] = (bf16)v;
            }
        }
    }
}

// ---------------------------------------------------------------------------
// QKV projection, pure-bf16 A (pre-cast), 64x128 tile, all-gload16 staging.
// V (z=2) written transposed directly to Vt via LDS.
// ---------------------------------------------------------------------------
__global__ __launch_bounds__(256) void gemm64_qkvb(const bf16* __restrict__ qb,
                                                   const bf16* __restrict__ kb,
                                                   const bf16* __restrict__ vb,
                                                   const bf16* __restrict__ WQt,
                                                   const bf16* __restrict__ WKt,
                                                   const bf16* __restrict__ WVt,
                                                   bf16* __restrict__ Qb,
                                                   bf16* __restrict__ Kb,
                                                   bf16* __restrict__ Vt)
{
    __shared__ bf16 sA[64 * 64];
    __shared__ bf16 sB[128 * 64];

    const bf16* A  = blockIdx.z == 0 ? qb  : blockIdx.z == 1 ? kb  : vb;
    const bf16* Bt = blockIdx.z == 0 ? WQt : blockIdx.z == 1 ? WKt : WVt;
    const int K = DIN;

    const int t    = threadIdx.x;
    const int lane = t & 63;
    const int wave = t >> 6;
    const int lr   = lane & 15;
    const int lq   = lane >> 4;

    const int m0 = blockIdx.y * 64;
    const int n0 = blockIdx.x * 128;

    const int srow = lane >> 3;
    const int scol = (lane & 7) * 8;

    f32x4 acc[4][2] = {};

    for (int k0 = 0; k0 < K; k0 += 64) {
        if (k0) __syncthreads();
#pragma unroll
        for (int i = 0; i < 2; ++i) {
            const int ch = wave * 2 + i;
            gload16(A + (size_t)(m0 + ch * 8 + srow) * K + k0 + scol, sA + ch * 512);
        }
#pragma unroll
        for (int i = 0; i < 4; ++i) {
            const int ch = wave * 4 + i;
            gload16(Bt + (size_t)(n0 + ch * 8 + srow) * K + k0 + scol, sB + ch * 512);
        }
        __syncthreads();

#pragma unroll
        for (int kk = 0; kk < 2; ++kk) {
            bf16x8 af[4], bfr[2];
#pragma unroll
            for (int x = 0; x < 4; ++x)
                af[x] = *reinterpret_cast<const bf16x8*>(&sA[(x * 16 + lr) * 64 + kk * 32 + lq * 8]);
#pragma unroll
            for (int n = 0; n < 2; ++n)
                bfr[n] = *reinterpret_cast<const bf16x8*>(&sB[(wave * 32 + n * 16 + lr) * 64 + kk * 32 + lq * 8]);
#pragma unroll
            for (int m = 0; m < 4; ++m)
#pragma unroll
                for (int n = 0; n < 2; ++n)
                    acc[m][n] = __builtin_amdgcn_mfma_f32_16x16x32_bf16(af[m], bfr[n], acc[m][n], 0, 0, 0);
        }
    }

    if (blockIdx.z < 2) {
        bf16* C = blockIdx.z == 0 ? Qb : Kb;
#pragma unroll
        for (int n = 0; n < 2; ++n) {
            const int col = n0 + wave * 32 + n * 16 + lr;
#pragma unroll
            for (int m = 0; m < 4; ++m) {
                const int rowb = m0 + m * 16 + lq * 4;
#pragma unroll
                for (int j = 0; j < 4; ++j)
                    C[(size_t)(rowb + j) * DIN + col] = (bf16)acc[m][n][j];
            }
        }
    } else {
        // V: transpose through LDS (reuse sB), write Vt[hd][l] coalesced.
        __syncthreads();
#pragma unroll
        for (int n = 0; n < 2; ++n)
#pragma unroll
            for (int m = 0; m < 4; ++m)
#pragma unroll
                for (int j = 0; j < 4; ++j)
                    sB[(wave * 32 + n * 16 + lr) * 64 + m * 16 + lq * 4 + j] = (bf16)acc[m][n][j];
        __syncthreads();
        const int c = t >> 1, half = t & 1;
#pragma unroll
        for (int qq = 0; qq < 4; ++qq) {
            const bf16x8 vv = *reinterpret_cast<const bf16x8*>(&sB[c * 64 + half * 32 + qq * 8]);
            *reinterpret_cast<bf16x8*>(Vt + (size_t)(n0 + c) * MROWS + m0 + half * 32 + qq * 8) = vv;
        }
    }
}

// ---------------------------------------------------------------------------
// Flash attention. ROUND-5: P stored TRANSPOSED (sPT[k][q], 16-col subtiles)
// with packed ds_write_b64 (8 writes/wave-tile vs 128 scalar b16/block-tile),
// PV A-frags read via ds_read_b64_tr_b16 (exact old pf mapping:
// k = s*32 + lq*8 + j, q = g*16 + lr), + s_setprio(1) around MFMA clusters.
// Everything else (staging, prefetch, QK, softmax math, epilogue) identical.
// ---------------------------------------------------------------------------
__global__ __launch_bounds__(256) void attn_kernel(const bf16* __restrict__ Qb,
                                                   const bf16* __restrict__ Kb,
                                                   const bf16* __restrict__ Vt,
                                                   const float* __restrict__ mask,
                                                   bf16* __restrict__ O,
                                                   const int* __restrict__ mzf)
{
    const int bi   = blockIdx.x;
    const int xcd  = bi & 7;
    const int slot = bi >> 3;
    const int pair = xcd * 4 + (slot >> 4);
    const int qt   = slot & 15;
    const int h    = pair >> 2;
    const int b    = pair & 3;

    const int t    = threadIdx.x;
    const int lane = t & 63;
    const int wave = t >> 6;
    const int lr   = lane & 15;
    const int lq   = lane >> 4;
    const int q0   = qt * 128;
    const bool useM = (*mzf != 0);

    __shared__ bf16 sK[64 * 72];
    __shared__ bf16 sV[64 * 72];
    __shared__ bf16 sPT[4][2048];        // per-wave P^T: [g][k=0..63][q 16-wide]
    __shared__ bf16 sM[128 * 68];

    bf16x8 qf[2][2];
#pragma unroll
    for (int g = 0; g < 2; ++g) {
        const int qrow = q0 + wave * 32 + g * 16 + lr;
        const bf16* qp = Qb + (size_t)(b * SEQ + qrow) * DIN + h * 64 + lq * 8;
        qf[g][0] = *reinterpret_cast<const bf16x8*>(qp);
        qf[g][1] = *reinterpret_cast<const bf16x8*>(qp + 32);
    }

    f32x4 o[2][4] = {};
    f32x4 lrow[2] = {};

    const int sr = t >> 2;
    const int sc = (t & 3) << 3;

    const bf16*  kbase = Kb + (size_t)(b * SEQ) * DIN + h * 64;
    const bf16*  vbase = Vt + (size_t)(h * 64 + sr) * MROWS + b * SEQ;
    const float* mbase = mask + ((size_t)b * SEQ + q0) * SEQ;

    constexpr float L2E = 1.4426950408889634f;
    constexpr float SCL = 0.125f * L2E;
    const bf16x8 ones = {(bf16)1.f, (bf16)1.f, (bf16)1.f, (bf16)1.f,
                         (bf16)1.f, (bf16)1.f, (bf16)1.f, (bf16)1.f};

    int4 kr0 = *reinterpret_cast<const int4*>(kbase + (size_t)sr * DIN + sc);
    int4 kr1 = *reinterpret_cast<const int4*>(kbase + (size_t)sr * DIN + sc + 32);
    int4 vr0 = *reinterpret_cast<const int4*>(vbase + sc);
    int4 vr1 = *reinterpret_cast<const int4*>(vbase + sc + 32);

    for (int tile = 0; tile < SEQ / 64; ++tile) {
        if (tile) __syncthreads();

        *reinterpret_cast<int4*>(&sK[sr * 72 + sc])      = kr0;
        *reinterpret_cast<int4*>(&sK[sr * 72 + sc + 32]) = kr1;
        *reinterpret_cast<int4*>(&sV[sr * 72 + sc])      = vr0;
        *reinterpret_cast<int4*>(&sV[sr * 72 + sc + 32]) = vr1;
        if (useM) {
            const int k0 = tile * 64;
#pragma unroll
            for (int i = 0; i < 8; ++i) {
                const int idx = t + 256 * i;
                const float4 mr = *reinterpret_cast<const float4*>(
                    mbase + (size_t)(idx >> 4) * SEQ + k0 + (idx & 15) * 4);
                bf16x4 mv;
                mv[0] = (bf16)(mr.x * L2E); mv[1] = (bf16)(mr.y * L2E);
                mv[2] = (bf16)(mr.z * L2E); mv[3] = (bf16)(mr.w * L2E);
                *reinterpret_cast<bf16x4*>(&sM[(idx >> 4) * 68 + (idx & 15) * 4]) = mv;
            }
        }

        if (tile + 1 < SEQ / 64) {
            const int k0 = (tile + 1) * 64;
            kr0 = *reinterpret_cast<const int4*>(kbase + (size_t)(k0 + sr) * DIN + sc);
            kr1 = *reinterpret_cast<const int4*>(kbase + (size_t)(k0 + sr) * DIN + sc + 32);
            vr0 = *reinterpret_cast<const int4*>(vbase + k0 + sc);
            vr1 = *reinterpret_cast<const int4*>(vbase + k0 + sc + 32);
        }
        __syncthreads();

        bf16x8 kf[2][4];
#pragma unroll
        for (int s = 0; s < 2; ++s)
#pragma unroll
            for (int ni = 0; ni < 4; ++ni)
                kf[s][ni] = *reinterpret_cast<const bf16x8*>(&sK[(ni * 16 + lr) * 72 + s * 32 + lq * 8]);

#pragma unroll
        for (int g = 0; g < 2; ++g) {
            f32x4 sf[4] = {};
            __builtin_amdgcn_s_setprio(1);
#pragma unroll
            for (int s = 0; s < 2; ++s)
#pragma unroll
                for (int ni = 0; ni < 4; ++ni)
                    sf[ni] = __builtin_amdgcn_mfma_f32_16x16x32_bf16(qf[g][s], kf[s][ni], sf[ni], 0, 0, 0);
            __builtin_amdgcn_s_setprio(0);

            // P^T packed write: lane's 4 j-values contiguous -> one b64/ni
#pragma unroll
            for (int ni = 0; ni < 4; ++ni) {
                bf16x4 pw;
                if (useM) {
#pragma unroll
                    for (int j = 0; j < 4; ++j) {
                        const float mval = (float)sM[(wave * 32 + g * 16 + lq * 4 + j) * 68 + ni * 16 + lr];
                        pw[j] = (bf16)exp2f(sf[ni][j] * SCL + mval);
                    }
                } else {
#pragma unroll
                    for (int j = 0; j < 4; ++j)
                        pw[j] = (bf16)exp2f(sf[ni][j] * SCL);
                }
                *reinterpret_cast<bf16x4*>(&sPT[wave][g * 1024 + (ni * 16 + lr) * 16 + lq * 4]) = pw;
            }
        }

        bf16x8 vfr[2][4];
#pragma unroll
        for (int s = 0; s < 2; ++s)
#pragma unroll
            for (int ni = 0; ni < 4; ++ni)
                vfr[s][ni] = *reinterpret_cast<const bf16x8*>(&sV[(ni * 16 + lr) * 72 + s * 32 + lq * 8]);

        // drain P^T writes (within-wave ordering; no barrier needed)
        asm volatile("s_waitcnt lgkmcnt(0)" ::: "memory");
        __builtin_amdgcn_sched_barrier(0);

#pragma unroll
        for (int g = 0; g < 2; ++g) {
            const bf16* pb = &sPT[wave][g * 1024 + lq * 128 + lr];
            const bf16x4 t00 = ds_tr16(pb);          // s=0, k = lq*8 + 0..3
            const bf16x4 t01 = ds_tr16(pb + 64);     // s=0, k = lq*8 + 4..7
            const bf16x4 t10 = ds_tr16(pb + 512);    // s=1
            const bf16x4 t11 = ds_tr16(pb + 576);
            asm volatile("s_waitcnt lgkmcnt(0)" ::: "memory");
            __builtin_amdgcn_sched_barrier(0);
            const bf16x8 pa0 = __builtin_shufflevector(t00, t01, 0, 1, 2, 3, 4, 5, 6, 7);
            const bf16x8 pa1 = __builtin_shufflevector(t10, t11, 0, 1, 2, 3, 4, 5, 6, 7);

            __builtin_amdgcn_s_setprio(1);
            f32x4 rs = {};
            rs = __builtin_amdgcn_mfma_f32_16x16x32_bf16(pa0, ones, rs, 0, 0, 0);
#pragma unroll
            for (int ni = 0; ni < 4; ++ni)
                o[g][ni] = __builtin_amdgcn_mfma_f32_16x16x32_bf16(pa0, vfr[0][ni], o[g][ni], 0, 0, 0);
            rs = __builtin_amdgcn_mfma_f32_16x16x32_bf16(pa1, ones, rs, 0, 0, 0);
#pragma unroll
            for (int ni = 0; ni < 4; ++ni)
                o[g][ni] = __builtin_amdgcn_mfma_f32_16x16x32_bf16(pa1, vfr[1][ni], o[g][ni], 0, 0, 0);
            __builtin_amdgcn_s_setprio(0);
#pragma unroll
            for (int j = 0; j < 4; ++j)
                lrow[g][j] += rs[j];
        }
    }

#pragma unroll
    for (int g = 0; g < 2; ++g)
#pragma unroll
        for (int ni = 0; ni < 4; ++ni)
#pragma unroll
            for (int j = 0; j < 4; ++j) {
                const int row = q0 + wave * 32 + g * 16 + lq * 4 + j;
                const int col = h * 64 + ni * 16 + lr;
                O[(size_t)(b * SEQ + row) * DIN + col] = (bf16)(o[g][ni][j] / lrow[g][j]);
            }
}

// ---------------------------------------------------------------------------
// FUSED GEMM + residual + LayerNorm for N=512 outputs (WO and W2 paths).
// Unchanged from round 4 (verified).
// ---------------------------------------------------------------------------
__global__ __launch_bounds__(512) void gemm_ln(const bf16* __restrict__ A,
                                               const bf16* __restrict__ Bt,
                                               const float* __restrict__ X,
                                               bf16* __restrict__ Onb,
                                               float* __restrict__ Onf,
                                               int K)
{
    __shared__ bf16 sA[2][32 * 64];
    __shared__ bf16 sB[2][512 * 64];
    __shared__ float sRed[32][8];
    __shared__ float sMu[32];
    __shared__ float sRstd[32];

    const int t    = threadIdx.x;
    const int lane = t & 63;
    const int w    = t >> 6;
    const int lr   = lane & 15;
    const int lq   = lane >> 4;
    const int srow = lane >> 3;
    const int scol = (lane & 7) * 8;

    const int m0 = blockIdx.x * 32;

    auto stage = [&](int s, int b) {
        const int k0 = s * 64;
#pragma unroll
        for (int i = 0; i < 8; ++i) {
            const int ch = w * 8 + i;
            gload16(Bt + (size_t)(ch * 8 + srow) * K + k0 + scol, &sB[b][ch * 512]);
        }
        if (w < 4)
            gload16(A + (size_t)(m0 + w * 8 + srow) * K + k0 + scol, &sA[b][w * 512]);
    };

    f32x4 acc[2][4] = {};
    const int steps = K / 64;

    stage(0, 0);
    __syncthreads();

    for (int s = 0; s < steps; ++s) {
        const int b = s & 1;
        if (s + 1 < steps) stage(s + 1, b ^ 1);

#pragma unroll
        for (int kk = 0; kk < 2; ++kk) {
            bf16x8 af[2], bfr[4];
#pragma unroll
            for (int m = 0; m < 2; ++m)
                af[m] = *reinterpret_cast<const bf16x8*>(&sA[b][(m * 16 + lr) * 64 + kk * 32 + lq * 8]);
#pragma unroll
            for (int n = 0; n < 4; ++n)
                bfr[n] = *reinterpret_cast<const bf16x8*>(&sB[b][(w * 64 + n * 16 + lr) * 64 + kk * 32 + lq * 8]);
#pragma unroll
            for (int m = 0; m < 2; ++m)
#pragma unroll
                for (int n = 0; n < 4; ++n)
                    acc[m][n] = __builtin_amdgcn_mfma_f32_16x16x32_bf16(af[m], bfr[n], acc[m][n], 0, 0, 0);
        }
        __syncthreads();
    }

#pragma unroll
    for (int m = 0; m < 2; ++m)
#pragma unroll
        for (int n = 0; n < 4; ++n)
#pragma unroll
            for (int j = 0; j < 4; ++j)
                acc[m][n][j] += X[(size_t)(m0 + m * 16 + lq * 4 + j) * DIN + w * 64 + n * 16 + lr];

#pragma unroll
    for (int m = 0; m < 2; ++m)
#pragma unroll
        for (int j = 0; j < 4; ++j) {
            float s = acc[m][0][j] + acc[m][1][j] + acc[m][2][j] + acc[m][3][j];
            s += __shfl_xor(s, 1); s += __shfl_xor(s, 2);
            s += __shfl_xor(s, 4); s += __shfl_xor(s, 8);
            if (lr == 0) sRed[m * 16 + lq * 4 + j][w] = s;
        }
    __syncthreads();
    if (t < 32) {
        float s = 0.f;
#pragma unroll
        for (int ww = 0; ww < 8; ++ww) s += sRed[t][ww];
        sMu[t] = s * (1.f / DIN);
    }
    __syncthreads();

#pragma unroll
    for (int m = 0; m < 2; ++m)
#pragma unroll
        for (int j = 0; j < 4; ++j) {
            const float mu = sMu[m * 16 + lq * 4 + j];
            float s = 0.f;
#pragma unroll
            for (int n = 0; n < 4; ++n) {
                const float d = acc[m][n][j] - mu;
                s += d * d;
            }
            s += __shfl_xor(s, 1); s += __shfl_xor(s, 2);
            s += __shfl_xor(s, 4); s += __shfl_xor(s, 8);
            if (lr == 0) sRed[m * 16 + lq * 4 + j][w] = s;
        }
    __syncthreads();
    if (t < 32) {
        float s = 0.f;
#pragma unroll
        for (int ww = 0; ww < 8; ++ww) s += sRed[t][ww];
        sRstd[t] = rsqrtf(s * (1.f / DIN) + 1e-5f);
    }
    __syncthreads();

#pragma unroll
    for (int m = 0; m < 2; ++m)
#pragma unroll
        for (int j = 0; j < 4; ++j) {
            const int rl = m * 16 + lq * 4 + j;
            const float mu = sMu[rl], rstd = sRstd[rl];
            const size_t rowoff = (size_t)(m0 + rl) * DIN;
#pragma unroll
            for (int n = 0; n < 4; ++n) {
                const float r = (acc[m][n][j] - mu) * rstd;
                const int col = w * 64 + n * 16 + lr;
                if (Onb) Onb[rowoff + col] = (bf16)r;
                if (Onf) Onf[rowoff + col] = r;
            }
        }
}

// ---------------------------------------------------------------------------
extern "C" void kernel_launch(void* const* d_in, const int* in_sizes, int n_in,
                              void* d_out, int out_size, void* d_ws, size_t ws_size,
                              hipStream_t stream)
{
    const float* query = (const float*)d_in[0];
    const float* key   = (const float*)d_in[1];
    const float* value = (const float*)d_in[2];
    const float* mask  = (const float*)d_in[3];
    const float* WQ    = (const float*)d_in[4];
    const float* WK    = (const float*)d_in[5];
    const float* WV    = (const float*)d_in[6];
    const float* WO    = (const float*)d_in[7];
    const float* W1    = (const float*)d_in[8];
    const float* W2    = (const float*)d_in[9];

    char* w = (char*)d_ws;
    size_t off = 0;
    auto carve2 = [&](size_t elems) { bf16* p = (bf16*)(w + off); off += elems * 2; return p; };
    auto carve4 = [&](size_t elems) { float* p = (float*)(w + off); off += elems * 4; return p; };

    bf16* Qb    = carve2((size_t)MROWS * DIN);
    bf16* Kb    = carve2((size_t)MROWS * DIN);
    bf16* Vb    = carve2((size_t)MROWS * DIN);   // attn output (Ob)
    bf16* Vt    = carve2((size_t)MROWS * DIN);
    bf16* Mid   = carve2((size_t)MROWS * DMID);
    float* Ln1f = carve4((size_t)MROWS * DIN);
    bf16* WQt   = carve2((size_t)DIN * DIN);
    bf16* WKt   = carve2((size_t)DIN * DIN);
    bf16* WVt   = carve2((size_t)DIN * DIN);
    bf16* WOt   = carve2((size_t)DIN * DIN);
    bf16* W1t   = carve2((size_t)DIN * DMID);
    bf16* W2t   = carve2((size_t)DMID * DIN);
    int*  mzf   = (int*)(w + off); off += 16;
    if (off > ws_size) return;

    bf16* Ob   = Vb;    // attn output
    bf16* Ln1b = Kb;    // LN1 bf16 (Kb dead after attention)
    // bf16 casts of q/k/v live in the (currently dead) Mid buffer:
    bf16* qb = Mid;
    bf16* kb = Mid + (size_t)MROWS * DIN;
    bf16* vb = Mid + (size_t)2 * MROWS * DIN;

    const dim3 blk(256);

    hipMemsetAsync(mzf, 0, 4, stream);

    // weights transpose + mask check + q/k/v bf16 cast (fused)
    tw_mask<<<dim3(7168), blk, 0, stream>>>(WQ, WK, WV, WO, W1, W2,
                                            WQt, WKt, WVt, WOt, W1t, W2t,
                                            query, key, value, qb, kb, vb,
                                            (const uint4*)mask, mzf);

    // Q/K/V projections (bf16 A, gload16 staging); V written transposed to Vt
    gemm64_qkvb<<<dim3(DIN / 128, MROWS / 64, 3), blk, 0, stream>>>(qb, kb, vb,
                                                                    WQt, WKt, WVt, Qb, Kb, Vt);

    // attention (P^T packed writes + tr-reads + setprio)
    attn_kernel<<<dim3(512), blk, 0, stream>>>(Qb, Kb, Vt, mask, Ob, mzf);

    // WO projection + residual(query) + LN  -> Ln1b (bf16) + Ln1f (fp32)
    gemm_ln<<<dim3(MROWS / 32), dim3(512), 0, stream>>>(Ob, WOt, query, Ln1b, Ln1f, DIN);

    // FFN up + ReLU   (Mid reused; qb/kb/vb dead by now)
    gemm128<1><<<dim3(DMID / 128, MROWS / 128), blk, 0, stream>>>(Ln1b, W1t, Mid, DMID, DIN);

    // W2 projection + residual(Ln1f) + LN -> fp32 output
    gemm_ln<<<dim3(MROWS / 32), dim3(512), 0, stream>>>(Mid, W2t, Ln1f,
                                                        (bf16*)nullptr, (float*)d_out, DMID);
}

// Round 6
// 359.592 us; speedup vs baseline: 1.0464x; 1.0464x over previous
//
#include <hip/hip_runtime.h>
#include <hip/hip_bf16.h>

using bf16 = __bf16;
typedef __bf16 bf16x4 __attribute__((ext_vector_type(4)));
typedef __bf16 bf16x8 __attribute__((ext_vector_type(8)));
typedef float f32x4 __attribute__((ext_vector_type(4)));
typedef float f32x16 __attribute__((ext_vector_type(16)));
typedef unsigned uint2v __attribute__((ext_vector_type(2)));

static constexpr int BATCH = 4;
static constexpr int SEQ   = 2048;
static constexpr int DIN   = 512;
static constexpr int NHEAD = 8;
static constexpr int DMID  = 2048;
static constexpr int MROWS = BATCH * SEQ;   // 8192

// ---------------------------------------------------------------------------
// global -> LDS direct DMA, 16 B per lane (global_load_lds_dwordx4).
// ---------------------------------------------------------------------------
__device__ __forceinline__ void gload16(const void* g, void* l)
{
    __builtin_amdgcn_global_load_lds(
        (const __attribute__((address_space(1))) unsigned int*)g,
        (__attribute__((address_space(3))) unsigned int*)l, 16, 0, 0);
}

// v_cvt_pk_bf16_f32: low16 = bf16(a), high16 = bf16(b)  (no builtin on gfx950)
__device__ __forceinline__ unsigned cvtpk(float a, float b)
{
    unsigned r;
    asm("v_cvt_pk_bf16_f32 %0, %1, %2" : "=v"(r) : "v"(a), "v"(b));
    return r;
}

// ---------------------------------------------------------------------------
// FUSED: six weight transposes (0..3071) + mask check (3072..4095) +
// q/k/v fp32->bf16 cast (4096..7167).  Unchanged from round 5 (verified).
// ---------------------------------------------------------------------------
__global__ __launch_bounds__(256) void tw_mask(
    const float* __restrict__ WQ, const float* __restrict__ WK,
    const float* __restrict__ WV, const float* __restrict__ WO,
    const float* __restrict__ W1, const float* __restrict__ W2,
    bf16* __restrict__ WQt, bf16* __restrict__ WKt, bf16* __restrict__ WVt,
    bf16* __restrict__ WOt, bf16* __restrict__ W1t, bf16* __restrict__ W2t,
    const float* __restrict__ q, const float* __restrict__ k,
    const float* __restrict__ v,
    bf16* __restrict__ qb, bf16* __restrict__ kb, bf16* __restrict__ vb,
    const uint4* __restrict__ mask, int* __restrict__ flag)
{
    const int bid = blockIdx.x;
    if (bid >= 4096) {
        const int idx = bid - 4096;
        const float* src = idx < 1024 ? q : idx < 2048 ? k : v;
        bf16*       dst = idx < 1024 ? qb : idx < 2048 ? kb : vb;
        const size_t b4 = (size_t)(idx & 1023) * 1024;
#pragma unroll
        for (int i = 0; i < 4; ++i) {
            const float4 f = reinterpret_cast<const float4*>(src)[b4 + i * 256 + threadIdx.x];
            bf16x4 h;
            h[0] = (bf16)f.x; h[1] = (bf16)f.y; h[2] = (bf16)f.z; h[3] = (bf16)f.w;
            reinterpret_cast<bf16x4*>(dst)[b4 + i * 256 + threadIdx.x] = h;
        }
        return;
    }
    if (bid >= 3072) {
        const uint4* p = mask + (size_t)(bid - 3072) * 4096;
        unsigned nz = 0;
#pragma unroll
        for (int i = 0; i < 16; ++i) {
            const uint4 u = p[i * 256 + threadIdx.x];
            nz |= u.x | u.y | u.z | u.w;
        }
        if (nz) atomicOr(flag, 1);
        return;
    }
    __shared__ float tile[32][33];
    const float* in; bf16* out; int ip, op, cx, ry;
    if (bid < 1024) {
        const int w = bid >> 8, idx = bid & 255;
        in  = w == 0 ? WQ  : w == 1 ? WK  : w == 2 ? WV  : WO;
        out = w == 0 ? WQt : w == 1 ? WKt : w == 2 ? WVt : WOt;
        ip = 512; op = 512; cx = idx & 15; ry = idx >> 4;
    } else if (bid < 2048) {
        const int idx = bid - 1024;
        in = W1; out = W1t; ip = 2048; op = 512; cx = idx & 63; ry = idx >> 6;
    } else {
        const int idx = bid - 2048;
        in = W2; out = W2t; ip = 512; op = 2048; cx = idx & 15; ry = idx >> 4;
    }
    const int c0 = cx * 32, r0 = ry * 32;
    const int tx = threadIdx.x & 31, ty = threadIdx.x >> 5;
    for (int i = 0; i < 32; i += 8)
        tile[ty + i][tx] = in[(size_t)(r0 + ty + i) * ip + c0 + tx];
    __syncthreads();
    for (int i = 0; i < 32; i += 8)
        out[(size_t)(c0 + ty + i) * op + r0 + tx] = (bf16)tile[tx][ty + i];
}

// ---------------------------------------------------------------------------
// 128x128-tile GEMM (m97 structure) for W1 (N=2048). Unchanged (verified).
// ---------------------------------------------------------------------------
template <int ACT>
__global__ __launch_bounds__(256) void gemm128(const bf16* __restrict__ A,
                                               const bf16* __restrict__ Bt,
                                               bf16* __restrict__ C,
                                               int N, int K)
{
    __shared__ bf16 sA[128 * 64];
    __shared__ bf16 sB[128 * 64];

    const int t    = threadIdx.x;
    const int lane = t & 63;
    const int wave = t >> 6;
    const int wm   = wave >> 1;
    const int wn   = wave & 1;
    const int lr   = lane & 15;
    const int lq   = lane >> 4;

    const int m0 = blockIdx.y * 128;
    const int n0 = blockIdx.x * 128;

    const int srow = lane >> 3;
    const int scol = (lane & 7) * 8;

    f32x4 acc[4][4] = {};

    for (int k0 = 0; k0 < K; k0 += 64) {
        if (k0) __syncthreads();
#pragma unroll
        for (int i = 0; i < 4; ++i) {
            const int ch = wave * 4 + i;
            const int r  = ch * 8 + srow;
            gload16(A  + (size_t)(m0 + r) * K + k0 + scol, sA + ch * 512);
            gload16(Bt + (size_t)(n0 + r) * K + k0 + scol, sB + ch * 512);
        }
        __syncthreads();

#pragma unroll
        for (int kk = 0; kk < 2; ++kk) {
            bf16x8 af[4], bfr[4];
#pragma unroll
            for (int x = 0; x < 4; ++x) {
                af[x]  = *reinterpret_cast<const bf16x8*>(&sA[(wm * 64 + x * 16 + lr) * 64 + kk * 32 + lq * 8]);
                bfr[x] = *reinterpret_cast<const bf16x8*>(&sB[(wn * 64 + x * 16 + lr) * 64 + kk * 32 + lq * 8]);
            }
#pragma unroll
            for (int m = 0; m < 4; ++m)
#pragma unroll
                for (int n = 0; n < 4; ++n)
                    acc[m][n] = __builtin_amdgcn_mfma_f32_16x16x32_bf16(af[m], bfr[n], acc[m][n], 0, 0, 0);
        }
    }

#pragma unroll
    for (int n = 0; n < 4; ++n) {
        const int col = n0 + wn * 64 + n * 16 + lr;
#pragma unroll
        for (int m = 0; m < 4; ++m) {
            const int rowb = m0 + wm * 64 + m * 16 + lq * 4;
#pragma unroll
            for (int j = 0; j < 4; ++j) {
                float v = acc[m][n][j];
                if (ACT == 1) v = v > 0.f ? v : 0.f;
                C[(size_t)(rowb + j) * N + col] = (bf16)v;
            }
        }
    }
}

// ---------------------------------------------------------------------------
// QKV projection, pure-bf16 A, 64x128 tile; V written transposed to Vt.
// Unchanged from round 5 (verified).
// ---------------------------------------------------------------------------
__global__ __launch_bounds__(256) void gemm64_qkvb(const bf16* __restrict__ qb,
                                                   const bf16* __restrict__ kb,
                                                   const bf16* __restrict__ vb,
                                                   const bf16* __restrict__ WQt,
                                                   const bf16* __restrict__ WKt,
                                                   const bf16* __restrict__ WVt,
                                                   bf16* __restrict__ Qb,
                                                   bf16* __restrict__ Kb,
                                                   bf16* __restrict__ Vt)
{
    __shared__ bf16 sA[64 * 64];
    __shared__ bf16 sB[128 * 64];

    const bf16* A  = blockIdx.z == 0 ? qb  : blockIdx.z == 1 ? kb  : vb;
    const bf16* Bt = blockIdx.z == 0 ? WQt : blockIdx.z == 1 ? WKt : WVt;
    const int K = DIN;

    const int t    = threadIdx.x;
    const int lane = t & 63;
    const int wave = t >> 6;
    const int lr   = lane & 15;
    const int lq   = lane >> 4;

    const int m0 = blockIdx.y * 64;
    const int n0 = blockIdx.x * 128;

    const int srow = lane >> 3;
    const int scol = (lane & 7) * 8;

    f32x4 acc[4][2] = {};

    for (int k0 = 0; k0 < K; k0 += 64) {
        if (k0) __syncthreads();
#pragma unroll
        for (int i = 0; i < 2; ++i) {
            const int ch = wave * 2 + i;
            gload16(A + (size_t)(m0 + ch * 8 + srow) * K + k0 + scol, sA + ch * 512);
        }
#pragma unroll
        for (int i = 0; i < 4; ++i) {
            const int ch = wave * 4 + i;
            gload16(Bt + (size_t)(n0 + ch * 8 + srow) * K + k0 + scol, sB + ch * 512);
        }
        __syncthreads();

#pragma unroll
        for (int kk = 0; kk < 2; ++kk) {
            bf16x8 af[4], bfr[2];
#pragma unroll
            for (int x = 0; x < 4; ++x)
                af[x] = *reinterpret_cast<const bf16x8*>(&sA[(x * 16 + lr) * 64 + kk * 32 + lq * 8]);
#pragma unroll
            for (int n = 0; n < 2; ++n)
                bfr[n] = *reinterpret_cast<const bf16x8*>(&sB[(wave * 32 + n * 16 + lr) * 64 + kk * 32 + lq * 8]);
#pragma unroll
            for (int m = 0; m < 4; ++m)
#pragma unroll
                for (int n = 0; n < 2; ++n)
                    acc[m][n] = __builtin_amdgcn_mfma_f32_16x16x32_bf16(af[m], bfr[n], acc[m][n], 0, 0, 0);
        }
    }

    if (blockIdx.z < 2) {
        bf16* C = blockIdx.z == 0 ? Qb : Kb;
#pragma unroll
        for (int n = 0; n < 2; ++n) {
            const int col = n0 + wave * 32 + n * 16 + lr;
#pragma unroll
            for (int m = 0; m < 4; ++m) {
                const int rowb = m0 + m * 16 + lq * 4;
#pragma unroll
                for (int j = 0; j < 4; ++j)
                    C[(size_t)(rowb + j) * DIN + col] = (bf16)acc[m][n][j];
            }
        }
    } else {
        __syncthreads();
#pragma unroll
        for (int n = 0; n < 2; ++n)
#pragma unroll
            for (int m = 0; m < 4; ++m)
#pragma unroll
                for (int j = 0; j < 4; ++j)
                    sB[(wave * 32 + n * 16 + lr) * 64 + m * 16 + lq * 4 + j] = (bf16)acc[m][n][j];
        __syncthreads();
        const int c = t >> 1, half = t & 1;
#pragma unroll
        for (int qq = 0; qq < 4; ++qq) {
            const bf16x8 vv = *reinterpret_cast<const bf16x8*>(&sB[c * 64 + half * 32 + qq * 8]);
            *reinterpret_cast<bf16x8*>(Vt + (size_t)(n0 + c) * MROWS + m0 + half * 32 + qq * 8) = vv;
        }
    }
}

// ---------------------------------------------------------------------------
// Flash attention, ROUND-6: swapped QK^T in 32x32 MFMA + in-register softmax.
//  - S^T = mfma_32x32x16(K, Q): q = lane&31 (lane-local), k' = (r&3)+8(r>>2)+4hi
//  - P stays in registers: exp2 on f32, pack via 16 cvt_pk + 8 permlane32_swap
//    per wave-tile -> PV A-fragments directly.  NO P LDS round-trip.
//  - K/V LDS [64][64] with chunk-XOR swizzle (write+read) -> conflict-free.
//  - row sums: 32 VALU adds + shfl_xor(32); broadcast via 512B sL at end.
//  - mask path (defensive; bench mask==0): direct global reads.
// LDS ~16.9 KB.  Staging/prefetch scheme identical to verified r3.
// ---------------------------------------------------------------------------
__global__ __launch_bounds__(256) void attn_kernel(const bf16* __restrict__ Qb,
                                                   const bf16* __restrict__ Kb,
                                                   const bf16* __restrict__ Vt,
                                                   const float* __restrict__ mask,
                                                   bf16* __restrict__ O,
                                                   const int* __restrict__ mzf)
{
    const int bi   = blockIdx.x;
    const int xcd  = bi & 7;
    const int slot = bi >> 3;
    const int pair = xcd * 4 + (slot >> 4);
    const int qt   = slot & 15;
    const int h    = pair >> 2;
    const int b    = pair & 3;

    const int t    = threadIdx.x;
    const int lane = t & 63;
    const int wave = t >> 6;
    const int l31  = lane & 31;
    const int hi   = lane >> 5;
    const int q0   = qt * 128;
    const bool useM = (*mzf != 0);

    __shared__ bf16 sK[64 * 64];
    __shared__ bf16 sV[64 * 64];
    __shared__ float sL[4][32];

    // Q fragments (B-operand): lane holds Q[q = l31][d = hi*8 + i + s*16]
    bf16x8 qf[4];
#pragma unroll
    for (int s = 0; s < 4; ++s)
        qf[s] = *reinterpret_cast<const bf16x8*>(
            Qb + (size_t)(b * SEQ + q0 + wave * 32 + l31) * DIN + h * 64 + s * 16 + hi * 8);

    f32x16 o0 = {}, o1 = {};
    float lacc = 0.f;

    const int sr = t >> 2;            // 0..63
    const int c1 = t & 3;             // chunk 0..3  (second int4 -> +4)

    const bf16* kbase = Kb + (size_t)(b * SEQ) * DIN + h * 64;
    const bf16* vbase = Vt + (size_t)(h * 64 + sr) * MROWS + b * SEQ;

    constexpr float L2E = 1.4426950408889634f;
    constexpr float SCL = 0.125f * L2E;

    // prefetch tile 0
    int4 kr0 = *reinterpret_cast<const int4*>(kbase + (size_t)sr * DIN + c1 * 8);
    int4 kr1 = *reinterpret_cast<const int4*>(kbase + (size_t)sr * DIN + c1 * 8 + 32);
    int4 vr0 = *reinterpret_cast<const int4*>(vbase + c1 * 8);
    int4 vr1 = *reinterpret_cast<const int4*>(vbase + c1 * 8 + 32);

    for (int tile = 0; tile < SEQ / 64; ++tile) {
        if (tile) __syncthreads();

        // swizzled staging writes: chunk ch at row r lands at (ch ^ (r&7))
        {
            const int x = sr & 7;
            *reinterpret_cast<int4*>(&sK[sr * 64 + ((c1    ) ^ x) * 8]) = kr0;
            *reinterpret_cast<int4*>(&sK[sr * 64 + ((c1 + 4) ^ x) * 8]) = kr1;
            *reinterpret_cast<int4*>(&sV[sr * 64 + ((c1    ) ^ x) * 8]) = vr0;
            *reinterpret_cast<int4*>(&sV[sr * 64 + ((c1 + 4) ^ x) * 8]) = vr1;
        }

        if (tile + 1 < SEQ / 64) {
            const int k0 = (tile + 1) * 64;
            kr0 = *reinterpret_cast<const int4*>(kbase + (size_t)(k0 + sr) * DIN + c1 * 8);
            kr1 = *reinterpret_cast<const int4*>(kbase + (size_t)(k0 + sr) * DIN + c1 * 8 + 32);
            vr0 = *reinterpret_cast<const int4*>(vbase + k0 + c1 * 8);
            vr1 = *reinterpret_cast<const int4*>(vbase + k0 + c1 * 8 + 32);
        }
        __syncthreads();

        // K fragments (A-operand): row = kb*32 + l31, chunk = hi + 2*s
        bf16x8 kf[2][4];
#pragma unroll
        for (int kb = 0; kb < 2; ++kb)
#pragma unroll
            for (int s = 0; s < 4; ++s) {
                const int r = kb * 32 + l31;
                kf[kb][s] = *reinterpret_cast<const bf16x8*>(
                    &sK[r * 64 + ((hi + 2 * s) ^ (r & 7)) * 8]);
            }
        // V fragments (B-operand): row = dt*32 + l31 (d), chunk = hi + 2*c (k)
        bf16x8 vf[2][4];
#pragma unroll
        for (int dt = 0; dt < 2; ++dt)
#pragma unroll
            for (int c = 0; c < 4; ++c) {
                const int r = dt * 32 + l31;
                vf[dt][c] = *reinterpret_cast<const bf16x8*>(
                    &sV[r * 64 + ((hi + 2 * c) ^ (r & 7)) * 8]);
            }

        // S^T = K @ Q^T : st[kb], D[row=k'][col=q=l31]
        f32x16 st0 = {}, st1 = {};
#pragma unroll
        for (int s = 0; s < 4; ++s) {
            st0 = __builtin_amdgcn_mfma_f32_32x32x16_bf16(kf[0][s], qf[s], st0, 0, 0, 0);
            st1 = __builtin_amdgcn_mfma_f32_32x32x16_bf16(kf[1][s], qf[s], st1, 0, 0, 0);
        }

        // softmax numerator in registers
        float p[32];
        if (useM) {
            const float* mrow = mask + ((size_t)(b * SEQ + q0 + wave * 32 + l31)) * SEQ + tile * 64;
#pragma unroll
            for (int r = 0; r < 16; ++r) {
                const int kk = (r & 3) + 8 * (r >> 2) + 4 * hi;
                p[r]      = exp2f(st0[r] * SCL + mrow[kk]      * L2E);
                p[16 + r] = exp2f(st1[r] * SCL + mrow[32 + kk] * L2E);
            }
        } else {
#pragma unroll
            for (int r = 0; r < 16; ++r) {
                p[r]      = exp2f(st0[r] * SCL);
                p[16 + r] = exp2f(st1[r] * SCL);
            }
        }
#pragma unroll
        for (int r = 0; r < 32; ++r) lacc += p[r];

        // pack to PV A-fragments: per kchunk, swap(cvtpk(p0,p1),cvtpk(p4,p5))
        // -> W0,W2 ; swap(cvtpk(p2,p3),cvtpk(p6,p7)) -> W1,W3
        bf16x8 pa[4];
#pragma unroll
        for (int c = 0; c < 4; ++c) {
            const int bse = c * 8;
            unsigned u0 = cvtpk(p[bse + 0], p[bse + 1]);
            unsigned u1 = cvtpk(p[bse + 2], p[bse + 3]);
            unsigned u2 = cvtpk(p[bse + 4], p[bse + 5]);
            unsigned u3 = cvtpk(p[bse + 6], p[bse + 7]);
            const uint2v r02 = __builtin_amdgcn_permlane32_swap(u0, u2, false, false);
            const uint2v r13 = __builtin_amdgcn_permlane32_swap(u1, u3, false, false);
            union { unsigned u[4]; bf16x8 v; } pk;
            pk.u[0] = r02.x; pk.u[1] = r13.x; pk.u[2] = r02.y; pk.u[3] = r13.y;
            pa[c] = pk.v;
        }

        // O += P V : D[row=q][col=d=l31]
#pragma unroll
        for (int c = 0; c < 4; ++c) {
            o0 = __builtin_amdgcn_mfma_f32_32x32x16_bf16(pa[c], vf[0][c], o0, 0, 0, 0);
            o1 = __builtin_amdgcn_mfma_f32_32x32x16_bf16(pa[c], vf[1][c], o1, 0, 0, 0);
        }
    }

    // row-sum completion + broadcast (lane l and l^32 hold complementary halves)
    lacc += __shfl_xor(lacc, 32);
    __syncthreads();                 // all tile LDS reads done; reuse not needed but safe
    if (lane < 32) sL[wave][lane] = lacc;
    __syncthreads();

#pragma unroll
    for (int r = 0; r < 16; ++r) {
        const int qr = (r & 3) + 8 * (r >> 2) + 4 * hi;
        const float inv = 1.f / sL[wave][qr];
        const size_t rowoff = (size_t)(b * SEQ + q0 + wave * 32 + qr) * DIN + h * 64;
        O[rowoff + l31]      = (bf16)(o0[r] * inv);
        O[rowoff + 32 + l31] = (bf16)(o1[r] * inv);
    }
}

// ---------------------------------------------------------------------------
// FUSED GEMM + residual + LayerNorm (WO and W2 paths). Unchanged (verified).
// ---------------------------------------------------------------------------
__global__ __launch_bounds__(512) void gemm_ln(const bf16* __restrict__ A,
                                               const bf16* __restrict__ Bt,
                                               const float* __restrict__ X,
                                               bf16* __restrict__ Onb,
                                               float* __restrict__ Onf,
                                               int K)
{
    __shared__ bf16 sA[2][32 * 64];
    __shared__ bf16 sB[2][512 * 64];
    __shared__ float sRed[32][8];
    __shared__ float sMu[32];
    __shared__ float sRstd[32];

    const int t    = threadIdx.x;
    const int lane = t & 63;
    const int w    = t >> 6;
    const int lr   = lane & 15;
    const int lq   = lane >> 4;
    const int srow = lane >> 3;
    const int scol = (lane & 7) * 8;

    const int m0 = blockIdx.x * 32;

    auto stage = [&](int s, int b) {
        const int k0 = s * 64;
#pragma unroll
        for (int i = 0; i < 8; ++i) {
            const int ch = w * 8 + i;
            gload16(Bt + (size_t)(ch * 8 + srow) * K + k0 + scol, &sB[b][ch * 512]);
        }
        if (w < 4)
            gload16(A + (size_t)(m0 + w * 8 + srow) * K + k0 + scol, &sA[b][w * 512]);
    };

    f32x4 acc[2][4] = {};
    const int steps = K / 64;

    stage(0, 0);
    __syncthreads();

    for (int s = 0; s < steps; ++s) {
        const int b = s & 1;
        if (s + 1 < steps) stage(s + 1, b ^ 1);

#pragma unroll
        for (int kk = 0; kk < 2; ++kk) {
            bf16x8 af[2], bfr[4];
#pragma unroll
            for (int m = 0; m < 2; ++m)
                af[m] = *reinterpret_cast<const bf16x8*>(&sA[b][(m * 16 + lr) * 64 + kk * 32 + lq * 8]);
#pragma unroll
            for (int n = 0; n < 4; ++n)
                bfr[n] = *reinterpret_cast<const bf16x8*>(&sB[b][(w * 64 + n * 16 + lr) * 64 + kk * 32 + lq * 8]);
#pragma unroll
            for (int m = 0; m < 2; ++m)
#pragma unroll
                for (int n = 0; n < 4; ++n)
                    acc[m][n] = __builtin_amdgcn_mfma_f32_16x16x32_bf16(af[m], bfr[n], acc[m][n], 0, 0, 0);
        }
        __syncthreads();
    }

#pragma unroll
    for (int m = 0; m < 2; ++m)
#pragma unroll
        for (int n = 0; n < 4; ++n)
#pragma unroll
            for (int j = 0; j < 4; ++j)
                acc[m][n][j] += X[(size_t)(m0 + m * 16 + lq * 4 + j) * DIN + w * 64 + n * 16 + lr];

#pragma unroll
    for (int m = 0; m < 2; ++m)
#pragma unroll
        for (int j = 0; j < 4; ++j) {
            float s = acc[m][0][j] + acc[m][1][j] + acc[m][2][j] + acc[m][3][j];
            s += __shfl_xor(s, 1); s += __shfl_xor(s, 2);
            s += __shfl_xor(s, 4); s += __shfl_xor(s, 8);
            if (lr == 0) sRed[m * 16 + lq * 4 + j][w] = s;
        }
    __syncthreads();
    if (t < 32) {
        float s = 0.f;
#pragma unroll
        for (int ww = 0; ww < 8; ++ww) s += sRed[t][ww];
        sMu[t] = s * (1.f / DIN);
    }
    __syncthreads();

#pragma unroll
    for (int m = 0; m < 2; ++m)
#pragma unroll
        for (int j = 0; j < 4; ++j) {
            const float mu = sMu[m * 16 + lq * 4 + j];
            float s = 0.f;
#pragma unroll
            for (int n = 0; n < 4; ++n) {
                const float d = acc[m][n][j] - mu;
                s += d * d;
            }
            s += __shfl_xor(s, 1); s += __shfl_xor(s, 2);
            s += __shfl_xor(s, 4); s += __shfl_xor(s, 8);
            if (lr == 0) sRed[m * 16 + lq * 4 + j][w] = s;
        }
    __syncthreads();
    if (t < 32) {
        float s = 0.f;
#pragma unroll
        for (int ww = 0; ww < 8; ++ww) s += sRed[t][ww];
        sRstd[t] = rsqrtf(s * (1.f / DIN) + 1e-5f);
    }
    __syncthreads();

#pragma unroll
    for (int m = 0; m < 2; ++m)
#pragma unroll
        for (int j = 0; j < 4; ++j) {
            const int rl = m * 16 + lq * 4 + j;
            const float mu = sMu[rl], rstd = sRstd[rl];
            const size_t rowoff = (size_t)(m0 + rl) * DIN;
#pragma unroll
            for (int n = 0; n < 4; ++n) {
                const float r = (acc[m][n][j] - mu) * rstd;
                const int col = w * 64 + n * 16 + lr;
                if (Onb) Onb[rowoff + col] = (bf16)r;
                if (Onf) Onf[rowoff + col] = r;
            }
        }
}

// ---------------------------------------------------------------------------
extern "C" void kernel_launch(void* const* d_in, const int* in_sizes, int n_in,
                              void* d_out, int out_size, void* d_ws, size_t ws_size,
                              hipStream_t stream)
{
    const float* query = (const float*)d_in[0];
    const float* key   = (const float*)d_in[1];
    const float* value = (const float*)d_in[2];
    const float* mask  = (const float*)d_in[3];
    const float* WQ    = (const float*)d_in[4];
    const float* WK    = (const float*)d_in[5];
    const float* WV    = (const float*)d_in[6];
    const float* WO    = (const float*)d_in[7];
    const float* W1    = (const float*)d_in[8];
    const float* W2    = (const float*)d_in[9];

    char* w = (char*)d_ws;
    size_t off = 0;
    auto carve2 = [&](size_t elems) { bf16* p = (bf16*)(w + off); off += elems * 2; return p; };
    auto carve4 = [&](size_t elems) { float* p = (float*)(w + off); off += elems * 4; return p; };

    bf16* Qb    = carve2((size_t)MROWS * DIN);
    bf16* Kb    = carve2((size_t)MROWS * DIN);
    bf16* Vb    = carve2((size_t)MROWS * DIN);   // attn output (Ob)
    bf16* Vt    = carve2((size_t)MROWS * DIN);
    bf16* Mid   = carve2((size_t)MROWS * DMID);
    float* Ln1f = carve4((size_t)MROWS * DIN);
    bf16* WQt   = carve2((size_t)DIN * DIN);
    bf16* WKt   = carve2((size_t)DIN * DIN);
    bf16* WVt   = carve2((size_t)DIN * DIN);
    bf16* WOt   = carve2((size_t)DIN * DIN);
    bf16* W1t   = carve2((size_t)DIN * DMID);
    bf16* W2t   = carve2((size_t)DMID * DIN);
    int*  mzf   = (int*)(w + off); off += 16;
    if (off > ws_size) return;

    bf16* Ob   = Vb;
    bf16* Ln1b = Kb;
    bf16* qb = Mid;
    bf16* kb = Mid + (size_t)MROWS * DIN;
    bf16* vb = Mid + (size_t)2 * MROWS * DIN;

    const dim3 blk(256);

    hipMemsetAsync(mzf, 0, 4, stream);

    tw_mask<<<dim3(7168), blk, 0, stream>>>(WQ, WK, WV, WO, W1, W2,
                                            WQt, WKt, WVt, WOt, W1t, W2t,
                                            query, key, value, qb, kb, vb,
                                            (const uint4*)mask, mzf);

    gemm64_qkvb<<<dim3(DIN / 128, MROWS / 64, 3), blk, 0, stream>>>(qb, kb, vb,
                                                                    WQt, WKt, WVt, Qb, Kb, Vt);

    // attention: swapped-QK^T 32x32, in-register softmax
    attn_kernel<<<dim3(512), blk, 0, stream>>>(Qb, Kb, Vt, mask, Ob, mzf);

    gemm_ln<<<dim3(MROWS / 32), dim3(512), 0, stream>>>(Ob, WOt, query, Ln1b, Ln1f, DIN);

    gemm128<1><<<dim3(DMID / 128, MROWS / 128), blk, 0, stream>>>(Ln1b, W1t, Mid, DMID, DIN);

    gemm_ln<<<dim3(MROWS / 32), dim3(512), 0, stream>>>(Mid, W2t, Ln1f,
                                                        (bf16*)nullptr, (float*)d_out, DMID);
}

// Round 7
// 350.260 us; speedup vs baseline: 1.0743x; 1.0266x over previous
//
#include <hip/hip_runtime.h>
#include <hip/hip_bf16.h>

using bf16 = __bf16;
typedef __bf16 bf16x4 __attribute__((ext_vector_type(4)));
typedef __bf16 bf16x8 __attribute__((ext_vector_type(8)));
typedef float f32x4 __attribute__((ext_vector_type(4)));
typedef float f32x16 __attribute__((ext_vector_type(16)));
typedef unsigned uint2v __attribute__((ext_vector_type(2)));

static constexpr int BATCH = 4;
static constexpr int SEQ   = 2048;
static constexpr int DIN   = 512;
static constexpr int NHEAD = 8;
static constexpr int DMID  = 2048;
static constexpr int MROWS = BATCH * SEQ;   // 8192

// ---------------------------------------------------------------------------
// global -> LDS direct DMA, 16 B per lane (global_load_lds_dwordx4).
// ---------------------------------------------------------------------------
__device__ __forceinline__ void gload16(const void* g, void* l)
{
    __builtin_amdgcn_global_load_lds(
        (const __attribute__((address_space(1))) unsigned int*)g,
        (__attribute__((address_space(3))) unsigned int*)l, 16, 0, 0);
}

// v_cvt_pk_bf16_f32: low16 = bf16(a), high16 = bf16(b)  (no builtin on gfx950)
__device__ __forceinline__ unsigned cvtpk(float a, float b)
{
    unsigned r;
    asm("v_cvt_pk_bf16_f32 %0, %1, %2" : "=v"(r) : "v"(a), "v"(b));
    return r;
}

// raw v_exp_f32 (libm exp2f expands to ~6 instr of denorm handling; softmax
// numerators never need denorm precision - flush-to-zero is fine here)
__device__ __forceinline__ float fexp2(float x)
{
    float r;
    asm("v_exp_f32 %0, %1" : "=v"(r) : "v"(x));
    return r;
}

// ---------------------------------------------------------------------------
// FUSED: six weight transposes (0..3071) + mask check (3072..4095) +
// q/k/v fp32->bf16 cast (4096..7167).  Unchanged (verified).
// ---------------------------------------------------------------------------
__global__ __launch_bounds__(256) void tw_mask(
    const float* __restrict__ WQ, const float* __restrict__ WK,
    const float* __restrict__ WV, const float* __restrict__ WO,
    const float* __restrict__ W1, const float* __restrict__ W2,
    bf16* __restrict__ WQt, bf16* __restrict__ WKt, bf16* __restrict__ WVt,
    bf16* __restrict__ WOt, bf16* __restrict__ W1t, bf16* __restrict__ W2t,
    const float* __restrict__ q, const float* __restrict__ k,
    const float* __restrict__ v,
    bf16* __restrict__ qb, bf16* __restrict__ kb, bf16* __restrict__ vb,
    const uint4* __restrict__ mask, int* __restrict__ flag)
{
    const int bid = blockIdx.x;
    if (bid >= 4096) {
        const int idx = bid - 4096;
        const float* src = idx < 1024 ? q : idx < 2048 ? k : v;
        bf16*       dst = idx < 1024 ? qb : idx < 2048 ? kb : vb;
        const size_t b4 = (size_t)(idx & 1023) * 1024;
#pragma unroll
        for (int i = 0; i < 4; ++i) {
            const float4 f = reinterpret_cast<const float4*>(src)[b4 + i * 256 + threadIdx.x];
            bf16x4 h;
            h[0] = (bf16)f.x; h[1] = (bf16)f.y; h[2] = (bf16)f.z; h[3] = (bf16)f.w;
            reinterpret_cast<bf16x4*>(dst)[b4 + i * 256 + threadIdx.x] = h;
        }
        return;
    }
    if (bid >= 3072) {
        const uint4* p = mask + (size_t)(bid - 3072) * 4096;
        unsigned nz = 0;
#pragma unroll
        for (int i = 0; i < 16; ++i) {
            const uint4 u = p[i * 256 + threadIdx.x];
            nz |= u.x | u.y | u.z | u.w;
        }
        if (nz) atomicOr(flag, 1);
        return;
    }
    __shared__ float tile[32][33];
    const float* in; bf16* out; int ip, op, cx, ry;
    if (bid < 1024) {
        const int w = bid >> 8, idx = bid & 255;
        in  = w == 0 ? WQ  : w == 1 ? WK  : w == 2 ? WV  : WO;
        out = w == 0 ? WQt : w == 1 ? WKt : w == 2 ? WVt : WOt;
        ip = 512; op = 512; cx = idx & 15; ry = idx >> 4;
    } else if (bid < 2048) {
        const int idx = bid - 1024;
        in = W1; out = W1t; ip = 2048; op = 512; cx = idx & 63; ry = idx >> 6;
    } else {
        const int idx = bid - 2048;
        in = W2; out = W2t; ip = 512; op = 2048; cx = idx & 15; ry = idx >> 4;
    }
    const int c0 = cx * 32, r0 = ry * 32;
    const int tx = threadIdx.x & 31, ty = threadIdx.x >> 5;
    for (int i = 0; i < 32; i += 8)
        tile[ty + i][tx] = in[(size_t)(r0 + ty + i) * ip + c0 + tx];
    __syncthreads();
    for (int i = 0; i < 32; i += 8)
        out[(size_t)(c0 + ty + i) * op + r0 + tx] = (bf16)tile[tx][ty + i];
}

// ---------------------------------------------------------------------------
// 128x128-tile GEMM (m97 structure) for W1 (N=2048). Unchanged (verified).
// ---------------------------------------------------------------------------
template <int ACT>
__global__ __launch_bounds__(256) void gemm128(const bf16* __restrict__ A,
                                               const bf16* __restrict__ Bt,
                                               bf16* __restrict__ C,
                                               int N, int K)
{
    __shared__ bf16 sA[128 * 64];
    __shared__ bf16 sB[128 * 64];

    const int t    = threadIdx.x;
    const int lane = t & 63;
    const int wave = t >> 6;
    const int wm   = wave >> 1;
    const int wn   = wave & 1;
    const int lr   = lane & 15;
    const int lq   = lane >> 4;

    const int m0 = blockIdx.y * 128;
    const int n0 = blockIdx.x * 128;

    const int srow = lane >> 3;
    const int scol = (lane & 7) * 8;

    f32x4 acc[4][4] = {};

    for (int k0 = 0; k0 < K; k0 += 64) {
        if (k0) __syncthreads();
#pragma unroll
        for (int i = 0; i < 4; ++i) {
            const int ch = wave * 4 + i;
            const int r  = ch * 8 + srow;
            gload16(A  + (size_t)(m0 + r) * K + k0 + scol, sA + ch * 512);
            gload16(Bt + (size_t)(n0 + r) * K + k0 + scol, sB + ch * 512);
        }
        __syncthreads();

#pragma unroll
        for (int kk = 0; kk < 2; ++kk) {
            bf16x8 af[4], bfr[4];
#pragma unroll
            for (int x = 0; x < 4; ++x) {
                af[x]  = *reinterpret_cast<const bf16x8*>(&sA[(wm * 64 + x * 16 + lr) * 64 + kk * 32 + lq * 8]);
                bfr[x] = *reinterpret_cast<const bf16x8*>(&sB[(wn * 64 + x * 16 + lr) * 64 + kk * 32 + lq * 8]);
            }
#pragma unroll
            for (int m = 0; m < 4; ++m)
#pragma unroll
                for (int n = 0; n < 4; ++n)
                    acc[m][n] = __builtin_amdgcn_mfma_f32_16x16x32_bf16(af[m], bfr[n], acc[m][n], 0, 0, 0);
        }
    }

#pragma unroll
    for (int n = 0; n < 4; ++n) {
        const int col = n0 + wn * 64 + n * 16 + lr;
#pragma unroll
        for (int m = 0; m < 4; ++m) {
            const int rowb = m0 + wm * 64 + m * 16 + lq * 4;
#pragma unroll
            for (int j = 0; j < 4; ++j) {
                float v = acc[m][n][j];
                if (ACT == 1) v = v > 0.f ? v : 0.f;
                C[(size_t)(rowb + j) * N + col] = (bf16)v;
            }
        }
    }
}

// ---------------------------------------------------------------------------
// QKV projection, pure-bf16 A, 64x128 tile; V written transposed to Vt.
// Unchanged (verified).
// ---------------------------------------------------------------------------
__global__ __launch_bounds__(256) void gemm64_qkvb(const bf16* __restrict__ qb,
                                                   const bf16* __restrict__ kb,
                                                   const bf16* __restrict__ vb,
                                                   const bf16* __restrict__ WQt,
                                                   const bf16* __restrict__ WKt,
                                                   const bf16* __restrict__ WVt,
                                                   bf16* __restrict__ Qb,
                                                   bf16* __restrict__ Kb,
                                                   bf16* __restrict__ Vt)
{
    __shared__ bf16 sA[64 * 64];
    __shared__ bf16 sB[128 * 64];

    const bf16* A  = blockIdx.z == 0 ? qb  : blockIdx.z == 1 ? kb  : vb;
    const bf16* Bt = blockIdx.z == 0 ? WQt : blockIdx.z == 1 ? WKt : WVt;
    const int K = DIN;

    const int t    = threadIdx.x;
    const int lane = t & 63;
    const int wave = t >> 6;
    const int lr   = lane & 15;
    const int lq   = lane >> 4;

    const int m0 = blockIdx.y * 64;
    const int n0 = blockIdx.x * 128;

    const int srow = lane >> 3;
    const int scol = (lane & 7) * 8;

    f32x4 acc[4][2] = {};

    for (int k0 = 0; k0 < K; k0 += 64) {
        if (k0) __syncthreads();
#pragma unroll
        for (int i = 0; i < 2; ++i) {
            const int ch = wave * 2 + i;
            gload16(A + (size_t)(m0 + ch * 8 + srow) * K + k0 + scol, sA + ch * 512);
        }
#pragma unroll
        for (int i = 0; i < 4; ++i) {
            const int ch = wave * 4 + i;
            gload16(Bt + (size_t)(n0 + ch * 8 + srow) * K + k0 + scol, sB + ch * 512);
        }
        __syncthreads();

#pragma unroll
        for (int kk = 0; kk < 2; ++kk) {
            bf16x8 af[4], bfr[2];
#pragma unroll
            for (int x = 0; x < 4; ++x)
                af[x] = *reinterpret_cast<const bf16x8*>(&sA[(x * 16 + lr) * 64 + kk * 32 + lq * 8]);
#pragma unroll
            for (int n = 0; n < 2; ++n)
                bfr[n] = *reinterpret_cast<const bf16x8*>(&sB[(wave * 32 + n * 16 + lr) * 64 + kk * 32 + lq * 8]);
#pragma unroll
            for (int m = 0; m < 4; ++m)
#pragma unroll
                for (int n = 0; n < 2; ++n)
                    acc[m][n] = __builtin_amdgcn_mfma_f32_16x16x32_bf16(af[m], bfr[n], acc[m][n], 0, 0, 0);
        }
    }

    if (blockIdx.z < 2) {
        bf16* C = blockIdx.z == 0 ? Qb : Kb;
#pragma unroll
        for (int n = 0; n < 2; ++n) {
            const int col = n0 + wave * 32 + n * 16 + lr;
#pragma unroll
            for (int m = 0; m < 4; ++m) {
                const int rowb = m0 + m * 16 + lq * 4;
#pragma unroll
                for (int j = 0; j < 4; ++j)
                    C[(size_t)(rowb + j) * DIN + col] = (bf16)acc[m][n][j];
            }
        }
    } else {
        __syncthreads();
#pragma unroll
        for (int n = 0; n < 2; ++n)
#pragma unroll
            for (int m = 0; m < 4; ++m)
#pragma unroll
                for (int j = 0; j < 4; ++j)
                    sB[(wave * 32 + n * 16 + lr) * 64 + m * 16 + lq * 4 + j] = (bf16)acc[m][n][j];
        __syncthreads();
        const int c = t >> 1, half = t & 1;
#pragma unroll
        for (int qq = 0; qq < 4; ++qq) {
            const bf16x8 vv = *reinterpret_cast<const bf16x8*>(&sB[c * 64 + half * 32 + qq * 8]);
            *reinterpret_cast<bf16x8*>(Vt + (size_t)(n0 + c) * MROWS + m0 + half * 32 + qq * 8) = vv;
        }
    }
}

// ---------------------------------------------------------------------------
// Flash attention, ROUND-7: r6 structure (swapped QK^T 32x32, in-register
// softmax via cvt_pk+permlane) with:
//  - 64 q-rows per WAVE (2 q-groups): kf/vf LDS reads + staging amortized 2x
//    (r6 was LDS-pipe ~49% busy); grid 256 (1 blk/CU), LDS 17.4 KB.
//  - raw v_exp_f32 instead of libm exp2f (~6 instr -> 2; r6 VALUBusy 58%).
//  - 4-way partial row sums (kills the 32-long serial add chain).
// ---------------------------------------------------------------------------
__global__ __launch_bounds__(256) void attn_kernel(const bf16* __restrict__ Qb,
                                                   const bf16* __restrict__ Kb,
                                                   const bf16* __restrict__ Vt,
                                                   const float* __restrict__ mask,
                                                   bf16* __restrict__ O,
                                                   const int* __restrict__ mzf)
{
    // XCD swizzle: 4 (b,h) pairs x 8 q-tiles per XCD
    const int bi   = blockIdx.x;
    const int xcd  = bi & 7;
    const int slot = bi >> 3;                 // 0..31
    const int pair = xcd * 4 + (slot >> 3);   // 0..31
    const int qt   = slot & 7;                // 0..7
    const int h    = pair >> 2;
    const int b    = pair & 3;

    const int t    = threadIdx.x;
    const int lane = t & 63;
    const int wave = t >> 6;
    const int l31  = lane & 31;
    const int hi   = lane >> 5;
    const int q0   = qt * 256;
    const bool useM = (*mzf != 0);

    __shared__ bf16 sK[64 * 64];
    __shared__ bf16 sV[64 * 64];
    __shared__ float sL[4][64];

    // Q fragments (B-operand), 2 q-groups: Q[q = wave*64 + g*32 + l31][d]
    bf16x8 qf[2][4];
#pragma unroll
    for (int g = 0; g < 2; ++g)
#pragma unroll
        for (int s = 0; s < 4; ++s)
            qf[g][s] = *reinterpret_cast<const bf16x8*>(
                Qb + (size_t)(b * SEQ + q0 + wave * 64 + g * 32 + l31) * DIN + h * 64 + s * 16 + hi * 8);

    f32x16 o[2][2] = {};
    float lacc[2] = {};

    const int sr = t >> 2;            // 0..63
    const int c1 = t & 3;             // chunk 0..3  (second int4 -> +4)

    const bf16* kbase = Kb + (size_t)(b * SEQ) * DIN + h * 64;
    const bf16* vbase = Vt + (size_t)(h * 64 + sr) * MROWS + b * SEQ;

    constexpr float L2E = 1.4426950408889634f;
    constexpr float SCL = 0.125f * L2E;

    // prefetch tile 0
    int4 kr0 = *reinterpret_cast<const int4*>(kbase + (size_t)sr * DIN + c1 * 8);
    int4 kr1 = *reinterpret_cast<const int4*>(kbase + (size_t)sr * DIN + c1 * 8 + 32);
    int4 vr0 = *reinterpret_cast<const int4*>(vbase + c1 * 8);
    int4 vr1 = *reinterpret_cast<const int4*>(vbase + c1 * 8 + 32);

    for (int tile = 0; tile < SEQ / 64; ++tile) {
        if (tile) __syncthreads();

        // swizzled staging writes: chunk ch at row r lands at (ch ^ (r&7))
        {
            const int x = sr & 7;
            *reinterpret_cast<int4*>(&sK[sr * 64 + ((c1    ) ^ x) * 8]) = kr0;
            *reinterpret_cast<int4*>(&sK[sr * 64 + ((c1 + 4) ^ x) * 8]) = kr1;
            *reinterpret_cast<int4*>(&sV[sr * 64 + ((c1    ) ^ x) * 8]) = vr0;
            *reinterpret_cast<int4*>(&sV[sr * 64 + ((c1 + 4) ^ x) * 8]) = vr1;
        }

        if (tile + 1 < SEQ / 64) {
            const int k0 = (tile + 1) * 64;
            kr0 = *reinterpret_cast<const int4*>(kbase + (size_t)(k0 + sr) * DIN + c1 * 8);
            kr1 = *reinterpret_cast<const int4*>(kbase + (size_t)(k0 + sr) * DIN + c1 * 8 + 32);
            vr0 = *reinterpret_cast<const int4*>(vbase + k0 + c1 * 8);
            vr1 = *reinterpret_cast<const int4*>(vbase + k0 + c1 * 8 + 32);
        }
        __syncthreads();

        // K fragments (A-operand): row = kb*32 + l31, chunk = hi + 2*s
        bf16x8 kf[2][4];
#pragma unroll
        for (int kb = 0; kb < 2; ++kb)
#pragma unroll
            for (int s = 0; s < 4; ++s) {
                const int r = kb * 32 + l31;
                kf[kb][s] = *reinterpret_cast<const bf16x8*>(
                    &sK[r * 64 + ((hi + 2 * s) ^ (r & 7)) * 8]);
            }
        // V fragments (B-operand): row = dt*32 + l31 (d), chunk = hi + 2*c (k)
        bf16x8 vf[2][4];
#pragma unroll
        for (int dt = 0; dt < 2; ++dt)
#pragma unroll
            for (int c = 0; c < 4; ++c) {
                const int r = dt * 32 + l31;
                vf[dt][c] = *reinterpret_cast<const bf16x8*>(
                    &sV[r * 64 + ((hi + 2 * c) ^ (r & 7)) * 8]);
            }

#pragma unroll
        for (int g = 0; g < 2; ++g) {
            // S^T = K @ Q^T : D[row=k'][col=q=l31]
            f32x16 st0 = {}, st1 = {};
#pragma unroll
            for (int s = 0; s < 4; ++s) {
                st0 = __builtin_amdgcn_mfma_f32_32x32x16_bf16(kf[0][s], qf[g][s], st0, 0, 0, 0);
                st1 = __builtin_amdgcn_mfma_f32_32x32x16_bf16(kf[1][s], qf[g][s], st1, 0, 0, 0);
            }

            // softmax numerator in registers (raw v_exp_f32)
            float p[32];
            if (useM) {
                const float* mrow = mask + ((size_t)(b * SEQ + q0 + wave * 64 + g * 32 + l31)) * SEQ + tile * 64;
#pragma unroll
                for (int r = 0; r < 16; ++r) {
                    const int kk = (r & 3) + 8 * (r >> 2) + 4 * hi;
                    p[r]      = fexp2(fmaf(st0[r], SCL, mrow[kk]      * L2E));
                    p[16 + r] = fexp2(fmaf(st1[r], SCL, mrow[32 + kk] * L2E));
                }
            } else {
#pragma unroll
                for (int r = 0; r < 16; ++r) {
                    p[r]      = fexp2(st0[r] * SCL);
                    p[16 + r] = fexp2(st1[r] * SCL);
                }
            }
            // 4-way partial sums (short dep chains)
            {
                float s0 = 0.f, s1 = 0.f, s2 = 0.f, s3 = 0.f;
#pragma unroll
                for (int r = 0; r < 8; ++r) {
                    s0 += p[r];
                    s1 += p[8 + r];
                    s2 += p[16 + r];
                    s3 += p[24 + r];
                }
                lacc[g] += (s0 + s1) + (s2 + s3);
            }

            // pack to PV A-fragments
            bf16x8 pa[4];
#pragma unroll
            for (int c = 0; c < 4; ++c) {
                const int bse = c * 8;
                unsigned u0 = cvtpk(p[bse + 0], p[bse + 1]);
                unsigned u1 = cvtpk(p[bse + 2], p[bse + 3]);
                unsigned u2 = cvtpk(p[bse + 4], p[bse + 5]);
                unsigned u3 = cvtpk(p[bse + 6], p[bse + 7]);
                const uint2v r02 = __builtin_amdgcn_permlane32_swap(u0, u2, false, false);
                const uint2v r13 = __builtin_amdgcn_permlane32_swap(u1, u3, false, false);
                union { unsigned u[4]; bf16x8 v; } pk;
                pk.u[0] = r02.x; pk.u[1] = r13.x; pk.u[2] = r02.y; pk.u[3] = r13.y;
                pa[c] = pk.v;
            }

            // O += P V : D[row=q][col=d=l31]
#pragma unroll
            for (int c = 0; c < 4; ++c) {
                o[g][0] = __builtin_amdgcn_mfma_f32_32x32x16_bf16(pa[c], vf[0][c], o[g][0], 0, 0, 0);
                o[g][1] = __builtin_amdgcn_mfma_f32_32x32x16_bf16(pa[c], vf[1][c], o[g][1], 0, 0, 0);
            }
        }
    }

    // row-sum completion: lane l and l^32 hold complementary k-halves
#pragma unroll
    for (int g = 0; g < 2; ++g)
        lacc[g] += __shfl_xor(lacc[g], 32);
    if (hi == 0) {
        sL[wave][l31]      = lacc[0];
        sL[wave][32 + l31] = lacc[1];
    }
    // same-wave write->read: compiler inserts lgkmcnt wait; no barrier needed

#pragma unroll
    for (int g = 0; g < 2; ++g)
#pragma unroll
        for (int r = 0; r < 16; ++r) {
            const int qr = (r & 3) + 8 * (r >> 2) + 4 * hi;
            const float inv = 1.f / sL[wave][g * 32 + qr];
            const size_t rowoff = (size_t)(b * SEQ + q0 + wave * 64 + g * 32 + qr) * DIN + h * 64;
            O[rowoff + l31]      = (bf16)(o[g][0][r] * inv);
            O[rowoff + 32 + l31] = (bf16)(o[g][1][r] * inv);
        }
}

// ---------------------------------------------------------------------------
// FUSED GEMM + residual + LayerNorm (WO and W2 paths). Unchanged (verified).
// ---------------------------------------------------------------------------
__global__ __launch_bounds__(512) void gemm_ln(const bf16* __restrict__ A,
                                               const bf16* __restrict__ Bt,
                                               const float* __restrict__ X,
                                               bf16* __restrict__ Onb,
                                               float* __restrict__ Onf,
                                               int K)
{
    __shared__ bf16 sA[2][32 * 64];
    __shared__ bf16 sB[2][512 * 64];
    __shared__ float sRed[32][8];
    __shared__ float sMu[32];
    __shared__ float sRstd[32];

    const int t    = threadIdx.x;
    const int lane = t & 63;
    const int w    = t >> 6;
    const int lr   = lane & 15;
    const int lq   = lane >> 4;
    const int srow = lane >> 3;
    const int scol = (lane & 7) * 8;

    const int m0 = blockIdx.x * 32;

    auto stage = [&](int s, int b) {
        const int k0 = s * 64;
#pragma unroll
        for (int i = 0; i < 8; ++i) {
            const int ch = w * 8 + i;
            gload16(Bt + (size_t)(ch * 8 + srow) * K + k0 + scol, &sB[b][ch * 512]);
        }
        if (w < 4)
            gload16(A + (size_t)(m0 + w * 8 + srow) * K + k0 + scol, &sA[b][w * 512]);
    };

    f32x4 acc[2][4] = {};
    const int steps = K / 64;

    stage(0, 0);
    __syncthreads();

    for (int s = 0; s < steps; ++s) {
        const int b = s & 1;
        if (s + 1 < steps) stage(s + 1, b ^ 1);

#pragma unroll
        for (int kk = 0; kk < 2; ++kk) {
            bf16x8 af[2], bfr[4];
#pragma unroll
            for (int m = 0; m < 2; ++m)
                af[m] = *reinterpret_cast<const bf16x8*>(&sA[b][(m * 16 + lr) * 64 + kk * 32 + lq * 8]);
#pragma unroll
            for (int n = 0; n < 4; ++n)
                bfr[n] = *reinterpret_cast<const bf16x8*>(&sB[b][(w * 64 + n * 16 + lr) * 64 + kk * 32 + lq * 8]);
#pragma unroll
            for (int m = 0; m < 2; ++m)
#pragma unroll
                for (int n = 0; n < 4; ++n)
                    acc[m][n] = __builtin_amdgcn_mfma_f32_16x16x32_bf16(af[m], bfr[n], acc[m][n], 0, 0, 0);
        }
        __syncthreads();
    }

#pragma unroll
    for (int m = 0; m < 2; ++m)
#pragma unroll
        for (int n = 0; n < 4; ++n)
#pragma unroll
            for (int j = 0; j < 4; ++j)
                acc[m][n][j] += X[(size_t)(m0 + m * 16 + lq * 4 + j) * DIN + w * 64 + n * 16 + lr];

#pragma unroll
    for (int m = 0; m < 2; ++m)
#pragma unroll
        for (int j = 0; j < 4; ++j) {
            float s = acc[m][0][j] + acc[m][1][j] + acc[m][2][j] + acc[m][3][j];
            s += __shfl_xor(s, 1); s += __shfl_xor(s, 2);
            s += __shfl_xor(s, 4); s += __shfl_xor(s, 8);
            if (lr == 0) sRed[m * 16 + lq * 4 + j][w] = s;
        }
    __syncthreads();
    if (t < 32) {
        float s = 0.f;
#pragma unroll
        for (int ww = 0; ww < 8; ++ww) s += sRed[t][ww];
        sMu[t] = s * (1.f / DIN);
    }
    __syncthreads();

#pragma unroll
    for (int m = 0; m < 2; ++m)
#pragma unroll
        for (int j = 0; j < 4; ++j) {
            const float mu = sMu[m * 16 + lq * 4 + j];
            float s = 0.f;
#pragma unroll
            for (int n = 0; n < 4; ++n) {
                const float d = acc[m][n][j] - mu;
                s += d * d;
            }
            s += __shfl_xor(s, 1); s += __shfl_xor(s, 2);
            s += __shfl_xor(s, 4); s += __shfl_xor(s, 8);
            if (lr == 0) sRed[m * 16 + lq * 4 + j][w] = s;
        }
    __syncthreads();
    if (t < 32) {
        float s = 0.f;
#pragma unroll
        for (int ww = 0; ww < 8; ++ww) s += sRed[t][ww];
        sRstd[t] = rsqrtf(s * (1.f / DIN) + 1e-5f);
    }
    __syncthreads();

#pragma unroll
    for (int m = 0; m < 2; ++m)
#pragma unroll
        for (int j = 0; j < 4; ++j) {
            const int rl = m * 16 + lq * 4 + j;
            const float mu = sMu[rl], rstd = sRstd[rl];
            const size_t rowoff = (size_t)(m0 + rl) * DIN;
#pragma unroll
            for (int n = 0; n < 4; ++n) {
                const float r = (acc[m][n][j] - mu) * rstd;
                const int col = w * 64 + n * 16 + lr;
                if (Onb) Onb[rowoff + col] = (bf16)r;
                if (Onf) Onf[rowoff + col] = r;
            }
        }
}

// ---------------------------------------------------------------------------
extern "C" void kernel_launch(void* const* d_in, const int* in_sizes, int n_in,
                              void* d_out, int out_size, void* d_ws, size_t ws_size,
                              hipStream_t stream)
{
    const float* query = (const float*)d_in[0];
    const float* key   = (const float*)d_in[1];
    const float* value = (const float*)d_in[2];
    const float* mask  = (const float*)d_in[3];
    const float* WQ    = (const float*)d_in[4];
    const float* WK    = (const float*)d_in[5];
    const float* WV    = (const float*)d_in[6];
    const float* WO    = (const float*)d_in[7];
    const float* W1    = (const float*)d_in[8];
    const float* W2    = (const float*)d_in[9];

    char* w = (char*)d_ws;
    size_t off = 0;
    auto carve2 = [&](size_t elems) { bf16* p = (bf16*)(w + off); off += elems * 2; return p; };
    auto carve4 = [&](size_t elems) { float* p = (float*)(w + off); off += elems * 4; return p; };

    bf16* Qb    = carve2((size_t)MROWS * DIN);
    bf16* Kb    = carve2((size_t)MROWS * DIN);
    bf16* Vb    = carve2((size_t)MROWS * DIN);   // attn output (Ob)
    bf16* Vt    = carve2((size_t)MROWS * DIN);
    bf16* Mid   = carve2((size_t)MROWS * DMID);
    float* Ln1f = carve4((size_t)MROWS * DIN);
    bf16* WQt   = carve2((size_t)DIN * DIN);
    bf16* WKt   = carve2((size_t)DIN * DIN);
    bf16* WVt   = carve2((size_t)DIN * DIN);
    bf16* WOt   = carve2((size_t)DIN * DIN);
    bf16* W1t   = carve2((size_t)DIN * DMID);
    bf16* W2t   = carve2((size_t)DMID * DIN);
    int*  mzf   = (int*)(w + off); off += 16;
    if (off > ws_size) return;

    bf16* Ob   = Vb;
    bf16* Ln1b = Kb;
    bf16* qb = Mid;
    bf16* kb = Mid + (size_t)MROWS * DIN;
    bf16* vb = Mid + (size_t)2 * MROWS * DIN;

    const dim3 blk(256);

    hipMemsetAsync(mzf, 0, 4, stream);

    tw_mask<<<dim3(7168), blk, 0, stream>>>(WQ, WK, WV, WO, W1, W2,
                                            WQt, WKt, WVt, WOt, W1t, W2t,
                                            query, key, value, qb, kb, vb,
                                            (const uint4*)mask, mzf);

    gemm64_qkvb<<<dim3(DIN / 128, MROWS / 64, 3), blk, 0, stream>>>(qb, kb, vb,
                                                                    WQt, WKt, WVt, Qb, Kb, Vt);

    // attention: 64 q-rows/wave, raw exp2, grid 256
    attn_kernel<<<dim3(256), blk, 0, stream>>>(Qb, Kb, Vt, mask, Ob, mzf);

    gemm_ln<<<dim3(MROWS / 32), dim3(512), 0, stream>>>(Ob, WOt, query, Ln1b, Ln1f, DIN);

    gemm128<1><<<dim3(DMID / 128, MROWS / 128), blk, 0, stream>>>(Ln1b, W1t, Mid, DMID, DIN);

    gemm_ln<<<dim3(MROWS / 32), dim3(512), 0, stream>>>(Mid, W2t, Ln1f,
                                                        (bf16*)nullptr, (float*)d_out, DMID);
}